// Round 4
// baseline (162.735 us; speedup 1.0000x reference)
//
#include <hip/hip_runtime.h>

// TripleGenerator: segmented triu-combinations.
// out = [idx_i (12M) | idx_j (12M) | idx_k (12M)] int32, 144 MB pure-write.
//
// R8: single-dispatch fusion of R7 (tied-best, nt stores, 48KB chunks).
// Normalized history: R4 1.842, R5 1.803, R6 1.853, R7 1.781 (total/fill).
// Every structural & cache-policy lever on the store stream is exhausted;
// the last addressable term is node count: starts_kernel's dispatch, its
// graph-node gap, and the 400KB workspace round-trip. Each j/k block now
// computes its <=104 starts in-prologue (lanes 0..103 binary-search pair_i
// while lanes 128+ load the 120B table; ~1.8us, hidden under the other
// resident blocks' store drain). Unlike R6 this keeps CHUNK=48KB and the
// R7 store body byte-identical. Predict ~-5..-10us normalized; if flat,
// the graph's conserved floor is reached (roofline per pre-commitment).

constexpr int K      = 16;                // neighbors/atom
constexpr int T_PER  = K * (K - 1) / 2;   // 120
constexpr int GROUPS = T_PER / 4;         // 30 int4 groups per atom
constexpr int BLK    = 256;
constexpr int ITERS  = 12;
constexpr int CHUNK  = BLK * ITERS;       // 3072 int4 groups per block (48 KB)

typedef int iv4 __attribute__((ext_vector_type(4)));

// Packed (u,v) template: entry r holds bytes {t=4r..4r+3} of pu in u[r], pv in v[r].
struct Tbl { unsigned u[GROUPS]; unsigned v[GROUPS]; };
constexpr Tbl make_tbl() {
    Tbl t{};
    int idx = 0;
    for (int a = 0; a < K; ++a)
        for (int b = a + 1; b < K; ++b) {
            t.u[idx / 4] |= (unsigned)a << ((idx % 4) * 8);
            t.v[idx / 4] |= (unsigned)b << ((idx % 4) * 8);
            ++idx;
        }
    return t;
}
__device__ constexpr Tbl TBL = make_tbl();

// Single fused kernel. Stream s = blockIdx%3 (i / j / k array); each block
// owns one contiguous CHUNK of one stream. j/k blocks compute their own
// starts: starts[a] = lower_bound(pair_i, a), identical to
// cumsum(counts)-counts for sorted pair_i (incl. empty segments).
__global__ __launch_bounds__(BLK)
void gen_fused(const int* __restrict__ pair_i, int* __restrict__ out,
               int m, int per_arr_groups) {
    const int s  = blockIdx.x % 3;   // stream id (mixes streams across XCDs)
    const int b  = blockIdx.x / 3;
    const int g0 = b * CHUNK;
    if (g0 >= per_arr_groups) return;

    iv4* __restrict__ o = (iv4*)out + (size_t)s * per_arr_groups;
    const bool full = (g0 + CHUNK) <= per_arr_groups;
    const int  gend = full ? (g0 + CHUNK) : per_arr_groups;

    if (s == 0) {
        // idx_i: pure compute, no loads, no barrier.
        if (full) {
            #pragma unroll
            for (int k = 0; k < ITERS; ++k) {
                const int g    = g0 + k * BLK + (int)threadIdx.x;
                const int atom = g / GROUPS;           // magic-mul const-div
                iv4 v; v[0] = atom; v[1] = atom; v[2] = atom; v[3] = atom;
                __builtin_nontemporal_store(v, &o[g]);
            }
        } else {
            for (int g = g0 + (int)threadIdx.x; g < gend; g += BLK) {
                const int atom = g / GROUPS;
                iv4 v; v[0] = atom; v[1] = atom; v[2] = atom; v[3] = atom;
                __builtin_nontemporal_store(v, &o[g]);
            }
        }
        return;
    }

    // idx_j / idx_k: prologue computes this block's starts + loads table.
    __shared__ int      s_st[CHUNK / GROUPS + 3];   // <=104 starts entries
    __shared__ unsigned s_tb[GROUPS];               // 120 B packed template
    const int a0 = g0 / GROUPS;
    const int na = (gend - 1) / GROUPS - a0 + 1;    // <=104
    if ((int)threadIdx.x < na) {
        const int a = a0 + (int)threadIdx.x;
        int lo = 0, hi = m;
        while (lo < hi) {                            // ~21 L2-hit steps
            const int mid = (lo + hi) >> 1;
            if (pair_i[mid] < a) lo = mid + 1; else hi = mid;
        }
        s_st[threadIdx.x] = lo;
    } else if ((int)threadIdx.x >= 128 && (int)threadIdx.x < 128 + GROUPS) {
        s_tb[threadIdx.x - 128] = (s == 1 ? TBL.u : TBL.v)[threadIdx.x - 128];
    }
    __syncthreads();

    if (full) {
        #pragma unroll
        for (int k = 0; k < ITERS; ++k) {
            const int g     = g0 + k * BLK + (int)threadIdx.x;
            const int atom  = g / GROUPS;
            const int r     = g - atom * GROUPS;
            const int start = s_st[atom - a0];       // LDS, broadcast-heavy
            const unsigned ub = s_tb[r];             // LDS, 30 distinct dwords/wave
            iv4 v;
            v[0] = start + (int)(ub & 0xff);
            v[1] = start + (int)((ub >> 8)  & 0xff);
            v[2] = start + (int)((ub >> 16) & 0xff);
            v[3] = start + (int)((ub >> 24) & 0xff);
            __builtin_nontemporal_store(v, &o[g]);
        }
    } else {
        for (int g = g0 + (int)threadIdx.x; g < gend; g += BLK) {
            const int atom  = g / GROUPS;
            const int r     = g - atom * GROUPS;
            const int start = s_st[atom - a0];
            const unsigned ub = s_tb[r];
            iv4 v;
            v[0] = start + (int)(ub & 0xff);
            v[1] = start + (int)((ub >> 8)  & 0xff);
            v[2] = start + (int)((ub >> 16) & 0xff);
            v[3] = start + (int)((ub >> 24) & 0xff);
            __builtin_nontemporal_store(v, &o[g]);
        }
    }
}

extern "C" void kernel_launch(void* const* d_in, const int* in_sizes, int n_in,
                              void* d_out, int out_size, void* d_ws, size_t ws_size,
                              hipStream_t stream) {
    const int* pair_i  = (const int*)d_in[0];
    const int  m       = in_sizes[0];   // n_atoms * K
    const int  n_atoms = m / K;         // 100,000

    int* out = (int*)d_out;
    const int per_arr_groups = n_atoms * GROUPS;   // 3,000,000

    // One dispatch, no workspace: 977 blocks/stream, 48KB contiguous each.
    const int nbs = (per_arr_groups + CHUNK - 1) / CHUNK;
    gen_fused<<<3 * nbs, BLK, 0, stream>>>(pair_i, out, m, per_arr_groups);
}